// Round 1
// baseline (176.686 us; speedup 1.0000x reference)
//
#include <hip/hip_runtime.h>

// PositionDropout: out[b,s,d] = scale(b,s) * x[b,s,d]
// scale(b,s) = bernoulli(prox) / (prox + 1e-5), bernoulli = JAX threefry2x32,
// key (0,42), partitionable random_bits (bits = o0 ^ o1, counter (0, row)).
// Bit-exact vs reference (verified rounds 1-6, absmax 0.03 = f32 mul assoc).
//
// R7: split into two streaming dispatches.
//   Evidence: rocprof shows fillBufferAligned (plain, branch-free store
//   stream) sustains 6.78 TB/s (85% peak) in this very graph, while the
//   fused branchy kernel's implied time (~47 us for ~134 MB) is only
//   ~2.9 TB/s. So: (1) zero_fill — fillBuffer-shaped plain-store zeroing
//   of the whole 100.7 MB output (~15 us @ fill rate); (2) scale_valid —
//   one wave/row, zero/padding rows exit with NO memory ops (output
//   already zero), valid rows (~34%) do 3 nt loads + scale + 3 stores
//   (~34 MB read + 34 MB write ~ 12 us). Extra cost: valid rows written
//   twice (+34 MB) + one launch; buys fill-rate on 75% of all bytes.

static constexpr int Bn = 64, Sn = 512, Dn = 768;
static constexpr int ROWS = Bn * Sn;            // 32768 rows
static constexpr int F4_PER_ROW = Dn / 4;       // 192 float4 per row
static constexpr int TOTAL_F4 = ROWS * F4_PER_ROW;   // 6,291,456

// zero_fill geometry: 2048 blocks x 256 threads x 12 stores = TOTAL_F4 exactly
static constexpr int ZF_BLOCKS = 2048;
static constexpr int ZF_STRIDE = ZF_BLOCKS * 256;        // 524288
static constexpr int ZF_ITERS  = TOTAL_F4 / ZF_STRIDE;   // 12

typedef float vfloat4 __attribute__((ext_vector_type(4)));

__device__ __forceinline__ unsigned rotl32(unsigned x, int d) {
  return (x << d) | (x >> (32 - d));
}

// Threefry-2x32, 20 rounds, key hard-coded to (0, 42) = jax.random.key(42)
__device__ __forceinline__ void threefry2x32_0_42(unsigned x0, unsigned x1,
                                                  unsigned& o0, unsigned& o1) {
  const unsigned ks0 = 0u;
  const unsigned ks1 = 42u;
  const unsigned ks2 = 0u ^ 42u ^ 0x1BD11BDAu;
  unsigned v0 = x0 + ks0;
  unsigned v1 = x1 + ks1;
#define RG(a, b, c, d)                       \
  v0 += v1; v1 = rotl32(v1, a); v1 ^= v0;    \
  v0 += v1; v1 = rotl32(v1, b); v1 ^= v0;    \
  v0 += v1; v1 = rotl32(v1, c); v1 ^= v0;    \
  v0 += v1; v1 = rotl32(v1, d); v1 ^= v0;
  RG(13, 15, 26, 6)   v0 += ks1; v1 += ks2 + 1u;
  RG(17, 29, 16, 24)  v0 += ks2; v1 += ks0 + 2u;
  RG(13, 15, 26, 6)   v0 += ks0; v1 += ks1 + 3u;
  RG(17, 29, 16, 24)  v0 += ks1; v1 += ks2 + 4u;
  RG(13, 15, 26, 6)   v0 += ks2; v1 += ks0 + 5u;
#undef RG
  o0 = v0;
  o1 = v1;
}

// Exactly mirrors the reference's f32 op sequence so u < prox matches bitwise.
__device__ __forceinline__ float row_scale(int row,
                                           const int* __restrict__ abi,
                                           const int* __restrict__ tl,
                                           const int* __restrict__ al) {
  unsigned o0, o1;
  threefry2x32_0_42(0u, (unsigned)row, o0, o1);
  unsigned bits = o0 ^ o1;

  int b = row >> 9;          // row / Sn
  int s = row & (Sn - 1);    // row % Sn
  float jf  = (float)s;
  float b0f = (float)abi[2 * b];
  float b1f = (float)abi[2 * b + 1];
  int   tli = tl[b];
  float tlf = (float)tli;
  float ctx = (float)(tli - al[b]);   // int sub then exact cvt

  float prox;
  if (jf < b0f)       prox = 1.0f - (b0f - jf) / ctx;
  else if (jf <= b1f) prox = 1.0f / ctx;
  else                prox = 1.0f - (jf - b1f) / ctx;
  prox = (jf < tlf) ? prox : 0.0f;
  prox = fminf(fmaxf(prox, 0.0f), 1.0f);

  // JAX uniform: bitcast((bits>>9)|0x3f800000) - 1.0  in [0,1)
  float u = __uint_as_float((bits >> 9) | 0x3f800000u) - 1.0f;
  float mask = (u < prox) ? 1.0f : 0.0f;
  return mask / (prox + 1e-5f);   // == 0.0f exactly when mask == 0
}

// Phase 1: fillBuffer-shaped zeroing of the full output. Branch-free,
// plain (cached) dwordx4 stores, each wave-instruction writes 1 KB
// contiguous. 2048 blocks = 8 blocks/CU.
__global__ void __launch_bounds__(256)
zero_fill(vfloat4* __restrict__ out) {
  int idx = blockIdx.x * 256 + threadIdx.x;
  vfloat4 z = {0.0f, 0.0f, 0.0f, 0.0f};
#pragma unroll
  for (int k = 0; k < ZF_ITERS; ++k)
    out[idx + k * ZF_STRIDE] = z;
}

// Phase 2: one wave per row. Zero/padding rows (~66%) exit immediately —
// zero_fill already produced their exact output. Valid rows stream
// 3 KB in (nt loads, no reuse) and 3 KB out.
__global__ void __launch_bounds__(256)
scale_valid(const vfloat4* __restrict__ x,
            const int* __restrict__ abi,
            const int* __restrict__ tl,
            const int* __restrict__ al,
            vfloat4* __restrict__ out) {
  int gtid = blockIdx.x * 256 + threadIdx.x;
  int row  = gtid >> 6;          // global wave id == row, 0..ROWS-1
  int lane = gtid & 63;

  float s = row_scale(row, abi, tl, al);   // wave-uniform

  if (s == 0.0f) return;                   // out already zeroed; no traffic

  int base = row * F4_PER_ROW + lane;      // 192 float4/row, 3 per lane
  vfloat4 v0 = __builtin_nontemporal_load(&x[base]);
  vfloat4 v1 = __builtin_nontemporal_load(&x[base + 64]);
  vfloat4 v2 = __builtin_nontemporal_load(&x[base + 128]);
  v0 *= s;
  v1 *= s;
  v2 *= s;
  out[base]       = v0;
  out[base + 64]  = v1;
  out[base + 128] = v2;
}

extern "C" void kernel_launch(void* const* d_in, const int* in_sizes, int n_in,
                              void* d_out, int out_size, void* d_ws, size_t ws_size,
                              hipStream_t stream) {
  const float* x  = (const float*)d_in[0];
  const int* abi  = (const int*)d_in[1];   // [B,2]
  const int* tl   = (const int*)d_in[2];   // [B]
  const int* al   = (const int*)d_in[3];   // [B]
  float* out = (float*)d_out;

  zero_fill<<<ZF_BLOCKS, 256, 0, stream>>>((vfloat4*)out);

  // ROWS waves -> ROWS*64 threads -> ROWS/4 blocks of 256
  scale_valid<<<ROWS / 4, 256, 0, stream>>>(
      (const vfloat4*)x, abi, tl, al, (vfloat4*)out);
}

// Round 2
// 164.207 us; speedup vs baseline: 1.0760x; 1.0760x over previous
//
#include <hip/hip_runtime.h>

// PositionDropout: out[b,s,d] = scale(b,s) * x[b,s,d]
// scale(b,s) = bernoulli(prox) / (prox + 1e-5), bernoulli = JAX threefry2x32,
// key (0,42), partitionable random_bits (bits = o0 ^ o1, counter (0, row)).
// Bit-exact vs reference (verified rounds 1-7, absmax 0.03 = f32 mul assoc).
//
// R8 = R6 fused structure (one dispatch, minimal traffic: 34 MB read +
// 100 MB write, wave-uniform zero-row skip) with PLAIN stores instead of
// nontemporal. Evidence: fillBufferAligned (plain stores) sustains 79-85%
// of peak in this graph; R6 (all-nt, 134 MB) implied ~2.9-4.5 TB/s; R7's
// plain-store kernels achieved higher BW over more traffic (neutral net).
// Store cache mode is the single variable changed vs R6. NT kept on loads
// only (pure streaming read, matches R7 scale_valid behavior).
// Floor: ~134 MB @ 6.3 TB/s ~ 21 us kernel-side.

static constexpr int Bn = 64, Sn = 512, Dn = 768;
static constexpr int ROWS = Bn * Sn;            // 32768 rows
static constexpr int F4_PER_ROW = Dn / 4;       // 192

typedef float vfloat4 __attribute__((ext_vector_type(4)));

__device__ __forceinline__ unsigned rotl32(unsigned x, int d) {
  return (x << d) | (x >> (32 - d));
}

// Threefry-2x32, 20 rounds, key hard-coded to (0, 42) = jax.random.key(42)
__device__ __forceinline__ void threefry2x32_0_42(unsigned x0, unsigned x1,
                                                  unsigned& o0, unsigned& o1) {
  const unsigned ks0 = 0u;
  const unsigned ks1 = 42u;
  const unsigned ks2 = 0u ^ 42u ^ 0x1BD11BDAu;
  unsigned v0 = x0 + ks0;
  unsigned v1 = x1 + ks1;
#define RG(a, b, c, d)                       \
  v0 += v1; v1 = rotl32(v1, a); v1 ^= v0;    \
  v0 += v1; v1 = rotl32(v1, b); v1 ^= v0;    \
  v0 += v1; v1 = rotl32(v1, c); v1 ^= v0;    \
  v0 += v1; v1 = rotl32(v1, d); v1 ^= v0;
  RG(13, 15, 26, 6)   v0 += ks1; v1 += ks2 + 1u;
  RG(17, 29, 16, 24)  v0 += ks2; v1 += ks0 + 2u;
  RG(13, 15, 26, 6)   v0 += ks0; v1 += ks1 + 3u;
  RG(17, 29, 16, 24)  v0 += ks1; v1 += ks2 + 4u;
  RG(13, 15, 26, 6)   v0 += ks2; v1 += ks0 + 5u;
#undef RG
  o0 = v0;
  o1 = v1;
}

// Exactly mirrors the reference's f32 op sequence so u < prox matches bitwise.
__device__ __forceinline__ float row_scale(int row,
                                           const int* __restrict__ abi,
                                           const int* __restrict__ tl,
                                           const int* __restrict__ al) {
  unsigned o0, o1;
  threefry2x32_0_42(0u, (unsigned)row, o0, o1);
  unsigned bits = o0 ^ o1;

  int b = row >> 9;          // row / Sn
  int s = row & (Sn - 1);    // row % Sn
  float jf  = (float)s;
  float b0f = (float)abi[2 * b];
  float b1f = (float)abi[2 * b + 1];
  int   tli = tl[b];
  float tlf = (float)tli;
  float ctx = (float)(tli - al[b]);   // int sub then exact cvt

  float prox;
  if (jf < b0f)       prox = 1.0f - (b0f - jf) / ctx;
  else if (jf <= b1f) prox = 1.0f / ctx;
  else                prox = 1.0f - (jf - b1f) / ctx;
  prox = (jf < tlf) ? prox : 0.0f;
  prox = fminf(fmaxf(prox, 0.0f), 1.0f);

  // JAX uniform: bitcast((bits>>9)|0x3f800000) - 1.0  in [0,1)
  float u = __uint_as_float((bits >> 9) | 0x3f800000u) - 1.0f;
  float mask = (u < prox) ? 1.0f : 0.0f;
  return mask / (prox + 1e-5f);   // == 0.0f exactly when mask == 0
}

// One wave per row. Block = 256 threads = 4 waves = 4 rows.
__global__ void __launch_bounds__(256)
pos_dropout_fused(const vfloat4* __restrict__ x,
                  const int* __restrict__ abi,
                  const int* __restrict__ tl,
                  const int* __restrict__ al,
                  vfloat4* __restrict__ out) {
  int gtid = blockIdx.x * 256 + threadIdx.x;
  int row  = gtid >> 6;          // global wave id == row, 0..ROWS-1
  int lane = gtid & 63;

  float s = row_scale(row, abi, tl, al);   // wave-uniform

  int base = row * F4_PER_ROW + lane;      // 192 float4/row, 3 per lane

  if (s == 0.0f) {
    // Dropped or padding row: output is exactly zero; skip the loads.
    // Plain stores — fillBuffer evidence: plain store stream = 85% peak.
    vfloat4 z = {0.0f, 0.0f, 0.0f, 0.0f};
    out[base]       = z;
    out[base + 64]  = z;
    out[base + 128] = z;
    return;
  }

  vfloat4 v0 = __builtin_nontemporal_load(&x[base]);
  vfloat4 v1 = __builtin_nontemporal_load(&x[base + 64]);
  vfloat4 v2 = __builtin_nontemporal_load(&x[base + 128]);
  v0 *= s;
  v1 *= s;
  v2 *= s;
  out[base]       = v0;
  out[base + 64]  = v1;
  out[base + 128] = v2;
}

extern "C" void kernel_launch(void* const* d_in, const int* in_sizes, int n_in,
                              void* d_out, int out_size, void* d_ws, size_t ws_size,
                              hipStream_t stream) {
  const float* x  = (const float*)d_in[0];
  const int* abi  = (const int*)d_in[1];   // [B,2]
  const int* tl   = (const int*)d_in[2];   // [B]
  const int* al   = (const int*)d_in[3];   // [B]
  float* out = (float*)d_out;

  // ROWS waves -> ROWS*64 threads -> ROWS/4 blocks of 256
  pos_dropout_fused<<<ROWS / 4, 256, 0, stream>>>(
      (const vfloat4*)x, abi, tl, al, (vfloat4*)out);
}